// Round 2
// baseline (402.642 us; speedup 1.0000x reference)
//
#include <hip/hip_runtime.h>
#include <hip/hip_bf16.h>

// B=4, L=2048, DIM=768, H=12, C=64.  M = B*L = 8192.  BH = 48.
// ws layout: Qf32[48][2048][64] (fp32) | K[48][2048][64] bf16 | Vt[48][64][2048] bf16
//            | AO[8192][768] bf16   -> 25.2 + 12.6 + 12.6 + 12.6 = 60 MB

typedef unsigned short u16;
typedef u16 u16x2 __attribute__((ext_vector_type(2)));
typedef u16 u16x4 __attribute__((ext_vector_type(4)));
typedef u16 u16x8 __attribute__((ext_vector_type(8)));
typedef short bf16x8 __attribute__((ext_vector_type(8)));
typedef float f32x4 __attribute__((ext_vector_type(4)));

#define MFMA16(acc, a, b) \
  asm("v_mfma_f32_16x16x32_bf16 %0, %1, %2, %0" : "+v"(acc) : "v"(a), "v"(b))

__device__ __forceinline__ u16 f2b(float f) {  // fp32 -> bf16 RNE
  unsigned u = __float_as_uint(f);
  return (u16)((u + 0x7fffu + ((u >> 16) & 1u)) >> 16);
}
__device__ __forceinline__ float b2f(u16 h) {
  return __uint_as_float(((unsigned)h) << 16);
}

// ---------------------------------------------------------------------------
// Kernel 1: qkv = x @ Wqkv with bf16x3 split-precision (hi/lo Dekker split of
// both operands, 3 MFMA products). 128x128 tile, BK=32, 4 waves.
// Q written fp32; K bf16; V bf16 transposed.
// ---------------------------------------------------------------------------
__global__ __launch_bounds__(256) void qkv_gemm_kernel(
    const float* __restrict__ X, const float* __restrict__ W,
    float* __restrict__ Qo, u16* __restrict__ Ko, u16* __restrict__ Vo) {
  __shared__ u16 Ah[128][40], Al[128][40];  // hi/lo A-tile, rows padded
  __shared__ u16 Bh[128][40], Bl[128][40];  // hi/lo B-tile, stored [col][k]
  const int tid = threadIdx.x;
  const int w = tid >> 6, l = tid & 63;
  const int llo = l & 15, lhi = l >> 4;
  const int m0 = blockIdx.x * 128;
  const int n0 = blockIdx.y * 128;
  const int wr = (w >> 1) * 64, wc = (w & 1) * 64;

  f32x4 acc[4][4] = {};

  const int arow = tid >> 1;
  const int akh  = (tid & 1) * 16;
  const int bcol = tid & 127;
  const int bkq  = (tid >> 7) * 16;

  for (int k0 = 0; k0 < 768; k0 += 32) {
    __syncthreads();
    {  // stage A-tile split hi/lo
      const float* xp = X + (size_t)(m0 + arow) * 768 + (k0 + akh);
      #pragma unroll
      for (int i = 0; i < 4; ++i) {
        float4 v = *(const float4*)(xp + 4 * i);
        u16 h0 = f2b(v.x), h1 = f2b(v.y), h2 = f2b(v.z), h3 = f2b(v.w);
        u16x4 hs = { h0, h1, h2, h3 };
        u16x4 ls = { f2b(v.x - b2f(h0)), f2b(v.y - b2f(h1)),
                     f2b(v.z - b2f(h2)), f2b(v.w - b2f(h3)) };
        *(u16x4*)&Ah[arow][akh + 4 * i] = hs;
        *(u16x4*)&Al[arow][akh + 4 * i] = ls;
      }
      // stage B-tile transposed, split hi/lo: Bs[col][k]
      const float* wp = W + (size_t)(k0 + bkq) * 2304 + (n0 + bcol);
      #pragma unroll
      for (int j = 0; j < 8; ++j) {
        float a0 = wp[(size_t)(2 * j) * 2304];
        float a1 = wp[(size_t)(2 * j + 1) * 2304];
        u16 h0 = f2b(a0), h1 = f2b(a1);
        u16x2 hs = { h0, h1 };
        u16x2 ls = { f2b(a0 - b2f(h0)), f2b(a1 - b2f(h1)) };
        *(u16x2*)&Bh[bcol][bkq + 2 * j] = hs;
        *(u16x2*)&Bl[bcol][bkq + 2 * j] = ls;
      }
    }
    __syncthreads();
    bf16x8 ah[4], al[4], bh[4], bl[4];
    #pragma unroll
    for (int i = 0; i < 4; ++i) {
      ah[i] = *(const bf16x8*)&Ah[wr + i * 16 + llo][lhi * 8];
      al[i] = *(const bf16x8*)&Al[wr + i * 16 + llo][lhi * 8];
    }
    #pragma unroll
    for (int n = 0; n < 4; ++n) {
      bh[n] = *(const bf16x8*)&Bh[wc + n * 16 + llo][lhi * 8];
      bl[n] = *(const bf16x8*)&Bl[wc + n * 16 + llo][lhi * 8];
    }
    #pragma unroll
    for (int i = 0; i < 4; ++i)
      #pragma unroll
      for (int n = 0; n < 4; ++n) {
        MFMA16(acc[i][n], ah[i], bh[n]);
        MFMA16(acc[i][n], al[i], bh[n]);
        MFMA16(acc[i][n], ah[i], bl[n]);
      }
  }

  // Epilogue: col -> (t,h,c); t uniform per block since 768 % 128 == 0.
  const int t = n0 / 768;
  #pragma unroll
  for (int i = 0; i < 4; ++i) {
    #pragma unroll
    for (int n = 0; n < 4; ++n) {
      const int gc = n0 + wc + n * 16 + llo;
      const int rem = gc - t * 768;
      const int h = rem >> 6, c = rem & 63;
      #pragma unroll
      for (int r = 0; r < 4; ++r) {
        const int row = m0 + wr + i * 16 + lhi * 4 + r;  // D: row=(l>>4)*4+reg
        const int b = row >> 11, lq = row & 2047;
        const size_t bh_ = (size_t)(b * 12 + h);
        const float fv = acc[i][n][r];
        if (t == 0)      Qo[(bh_ * 2048 + lq) * 64 + c] = fv;          // fp32
        else if (t == 1) Ko[(bh_ * 2048 + lq) * 64 + c] = f2b(fv);
        else             Vo[(bh_ * 64 + c) * 2048 + lq] = f2b(fv);     // V^T
      }
    }
  }
}

// ---------------------------------------------------------------------------
// Kernel 2: flash attention (no logit scale). Q consumed from fp32 via hi/lo
// register split; QK^T uses 2 products (q_hi*k + q_lo*k). 4 waves x 16 q-rows,
// KV tile = 64 keys in LDS.
// ---------------------------------------------------------------------------
__global__ __launch_bounds__(256) void attn_kernel(
    const float* __restrict__ Qf, const u16* __restrict__ Km,
    const u16* __restrict__ Vt, u16* __restrict__ AO) {
  __shared__ u16 Ks[64][72];      // [key][c], padded -> 2-way alias only
  __shared__ u16 Vs[64][72];      // [c][key]
  __shared__ u16 Ps[4][16][72];   // per-wave P round-trip: [q][key]
  const int tid = threadIdx.x;
  const int w = tid >> 6, l = tid & 63;
  const int llo = l & 15, lhi = l >> 4;
  const int bh = blockIdx.y;
  const int q0 = blockIdx.x * 64 + w * 16;

  // Q fragments: A[q=llo][c=lhi*8+j (+32)], split hi/lo from fp32
  const float* Qp = Qf + ((size_t)bh * 2048 + q0 + llo) * 64 + lhi * 8;
  bf16x8 qf0h, qf0l, qf1h, qf1l;
  #pragma unroll
  for (int j = 0; j < 8; ++j) {
    float a = Qp[j], b = Qp[32 + j];
    u16 ha = f2b(a), hb = f2b(b);
    qf0h[j] = (short)ha; qf0l[j] = (short)f2b(a - b2f(ha));
    qf1h[j] = (short)hb; qf1l[j] = (short)f2b(b - b2f(hb));
  }

  float mrow[4], lsum[4];
  f32x4 o_acc[4] = {};
  #pragma unroll
  for (int r = 0; r < 4; ++r) { mrow[r] = -1e30f; lsum[r] = 0.f; }

  for (int kt = 0; kt < 32; ++kt) {
    const int kb = kt * 64;
    __syncthreads();
    #pragma unroll
    for (int i = 0; i < 2; ++i) {  // cooperative KV staging (16B chunks)
      const int idx = tid + i * 256;
      const int r = idx >> 3, ch = (idx & 7) * 8;
      *(u16x8*)&Ks[r][ch] = *(const u16x8*)(Km + ((size_t)bh * 2048 + kb + r) * 64 + ch);
      *(u16x8*)&Vs[r][ch] = *(const u16x8*)(Vt + ((size_t)bh * 64 + r) * 2048 + kb + ch);
    }
    __syncthreads();

    // S = Q K^T : D col=key(llo), row=q(lhi*4+reg); 2-product split on Q
    f32x4 s_acc[4] = {};
    #pragma unroll
    for (int kb4 = 0; kb4 < 4; ++kb4) {
      bf16x8 kf0 = *(const bf16x8*)&Ks[kb4 * 16 + llo][lhi * 8];
      bf16x8 kf1 = *(const bf16x8*)&Ks[kb4 * 16 + llo][32 + lhi * 8];
      MFMA16(s_acc[kb4], qf0h, kf0);
      MFMA16(s_acc[kb4], qf0l, kf0);
      MFMA16(s_acc[kb4], qf1h, kf1);
      MFMA16(s_acc[kb4], qf1l, kf1);
    }

    // online softmax, per q-row (reg r), 16-lane group reduction
    #pragma unroll
    for (int r = 0; r < 4; ++r) {
      float tm = fmaxf(fmaxf(s_acc[0][r], s_acc[1][r]),
                       fmaxf(s_acc[2][r], s_acc[3][r]));
      tm = fmaxf(tm, __shfl_xor(tm, 1));
      tm = fmaxf(tm, __shfl_xor(tm, 2));
      tm = fmaxf(tm, __shfl_xor(tm, 4));
      tm = fmaxf(tm, __shfl_xor(tm, 8));
      const float mn = fmaxf(mrow[r], tm);
      const float scale = __expf(mrow[r] - mn);
      mrow[r] = mn;
      float rs = 0.f;
      #pragma unroll
      for (int kb4 = 0; kb4 < 4; ++kb4) {
        const float p = __expf(s_acc[kb4][r] - mn);
        rs += p;
        Ps[w][lhi * 4 + r][kb4 * 16 + llo] = f2b(p);
      }
      rs += __shfl_xor(rs, 1);
      rs += __shfl_xor(rs, 2);
      rs += __shfl_xor(rs, 4);
      rs += __shfl_xor(rs, 8);
      lsum[r] = lsum[r] * scale + rs;
      #pragma unroll
      for (int cb = 0; cb < 4; ++cb) o_acc[cb][r] *= scale;
    }

    // O += P V : same-wave LDS round-trip (compiler inserts lgkmcnt waits)
    const bf16x8 pa0 = *(const bf16x8*)&Ps[w][llo][lhi * 8];
    const bf16x8 pa1 = *(const bf16x8*)&Ps[w][llo][32 + lhi * 8];
    #pragma unroll
    for (int cb = 0; cb < 4; ++cb) {
      bf16x8 vf0 = *(const bf16x8*)&Vs[cb * 16 + llo][lhi * 8];
      bf16x8 vf1 = *(const bf16x8*)&Vs[cb * 16 + llo][32 + lhi * 8];
      MFMA16(o_acc[cb], pa0, vf0);
      MFMA16(o_acc[cb], pa1, vf1);
    }
  }

  // normalize + write attn output [b][l][h*64+c] bf16
  const int b = bh / 12, h = bh % 12;
  #pragma unroll
  for (int cb = 0; cb < 4; ++cb)
    #pragma unroll
    for (int r = 0; r < 4; ++r) {
      const float val = o_acc[cb][r] / lsum[r];
      AO[((size_t)(b * 2048 + q0 + lhi * 4 + r)) * 768 + h * 64 + cb * 16 + llo] = f2b(val);
    }
}

// ---------------------------------------------------------------------------
// Kernel 3: out = AO @ Wo + bo  (8192x768 * 768x768), fp32 out.
// ---------------------------------------------------------------------------
__global__ __launch_bounds__(256) void out_gemm_kernel(
    const u16* __restrict__ A, const float* __restrict__ W,
    const float* __restrict__ bias, float* __restrict__ Out) {
  __shared__ u16 As[128][40];
  __shared__ u16 Bs[128][40];
  const int tid = threadIdx.x;
  const int w = tid >> 6, l = tid & 63;
  const int llo = l & 15, lhi = l >> 4;
  const int m0 = blockIdx.x * 128;
  const int n0 = blockIdx.y * 128;
  const int wr = (w >> 1) * 64, wc = (w & 1) * 64;

  f32x4 acc[4][4] = {};

  const int arow = tid >> 1;
  const int akh  = (tid & 1) * 16;
  const int bcol = tid & 127;
  const int bkq  = (tid >> 7) * 16;

  for (int k0 = 0; k0 < 768; k0 += 32) {
    __syncthreads();
    {
      const u16* ap = A + (size_t)(m0 + arow) * 768 + (k0 + akh);
      #pragma unroll
      for (int i = 0; i < 2; ++i)
        *(u16x8*)&As[arow][akh + 8 * i] = *(const u16x8*)(ap + 8 * i);
      const float* wp = W + (size_t)(k0 + bkq) * 768 + (n0 + bcol);
      #pragma unroll
      for (int j = 0; j < 8; ++j) {
        float a0 = wp[(size_t)(2 * j) * 768];
        float a1 = wp[(size_t)(2 * j + 1) * 768];
        u16x2 s2 = { f2b(a0), f2b(a1) };
        *(u16x2*)&Bs[bcol][bkq + 2 * j] = s2;
      }
    }
    __syncthreads();
    bf16x8 af[4], bfr[4];
    #pragma unroll
    for (int i = 0; i < 4; ++i) af[i] = *(const bf16x8*)&As[wr + i * 16 + llo][lhi * 8];
    #pragma unroll
    for (int n = 0; n < 4; ++n) bfr[n] = *(const bf16x8*)&Bs[wc + n * 16 + llo][lhi * 8];
    #pragma unroll
    for (int i = 0; i < 4; ++i)
      #pragma unroll
      for (int n = 0; n < 4; ++n)
        MFMA16(acc[i][n], af[i], bfr[n]);
  }

  #pragma unroll
  for (int i = 0; i < 4; ++i)
    #pragma unroll
    for (int n = 0; n < 4; ++n) {
      const int gc = n0 + wc + n * 16 + llo;
      const float bb = bias[gc];
      #pragma unroll
      for (int r = 0; r < 4; ++r) {
        const int row = m0 + wr + i * 16 + lhi * 4 + r;
        Out[(size_t)row * 768 + gc] = acc[i][n][r] + bb;
      }
    }
}

// ---------------------------------------------------------------------------
extern "C" void kernel_launch(void* const* d_in, const int* in_sizes, int n_in,
                              void* d_out, int out_size, void* d_ws, size_t ws_size,
                              hipStream_t stream) {
  const float* x    = (const float*)d_in[0];
  const float* Wqkv = (const float*)d_in[1];
  const float* Wo   = (const float*)d_in[2];
  const float* bo   = (const float*)d_in[3];
  float* out = (float*)d_out;

  const size_t SEG = (size_t)48 * 2048 * 64;  // 6291456 elements
  float* qf = (float*)d_ws;        // fp32 Q
  u16* k  = (u16*)(qf + SEG);
  u16* v  = k + SEG;
  u16* ao = v + SEG;               // [8192][768] bf16

  qkv_gemm_kernel<<<dim3(64, 18), 256, 0, stream>>>(x, Wqkv, qf, k, v);
  attn_kernel<<<dim3(32, 48), 256, 0, stream>>>(qf, k, v, ao);
  out_gemm_kernel<<<dim3(64, 6), 256, 0, stream>>>(ao, Wo, bo, out);
}

// Round 3
// 314.046 us; speedup vs baseline: 1.2821x; 1.2821x over previous
//
#include <hip/hip_runtime.h>
#include <hip/hip_bf16.h>

// B=4, L=2048, DIM=768, H=12, C=64.  M = B*L = 8192.  BH = 48.
// ws (u16 units), SEG = 48*2048*64 = 6291456:
//   Qf32[2S] | K[S] | Vt[S] | Xh[S] (reused as AO after qkv) | Xl[S]
//   | WtH[2304*768] | WtL[2304*768] | Wot[768*768]   ~= 84 MB

typedef unsigned short u16;
typedef u16 u16x2 __attribute__((ext_vector_type(2)));
typedef u16 u16x4 __attribute__((ext_vector_type(4)));
typedef u16 u16x8 __attribute__((ext_vector_type(8)));
typedef short bf16x8 __attribute__((ext_vector_type(8)));
typedef float f32x4 __attribute__((ext_vector_type(4)));

#define MFMA16(acc, a, b) \
  asm("v_mfma_f32_16x16x32_bf16 %0, %1, %2, %0" : "+v"(acc) : "v"(a), "v"(b))

__device__ __forceinline__ u16 f2b(float f) {  // fp32 -> bf16 RNE
  unsigned u = __float_as_uint(f);
  return (u16)((u + 0x7fffu + ((u >> 16) & 1u)) >> 16);
}
__device__ __forceinline__ float b2f(u16 h) {
  return __uint_as_float(((unsigned)h) << 16);
}

// async global->LDS, 16B per lane. LDS dest must be wave-uniform base.
__device__ __forceinline__ void gload16(const u16* g, u16* l) {
  __builtin_amdgcn_global_load_lds(
      (const __attribute__((address_space(1))) unsigned*)g,
      (__attribute__((address_space(3))) unsigned*)l, 16, 0, 0);
}

// ---------------------------------------------------------------------------
// prep_x: x fp32 [8192][768] -> Xh, Xl bf16 (Dekker hi/lo). 4 elems/thread.
// ---------------------------------------------------------------------------
__global__ __launch_bounds__(256) void prep_x_kernel(
    const float* __restrict__ X, u16* __restrict__ Xh, u16* __restrict__ Xl) {
  const size_t i = ((size_t)blockIdx.x * 256 + threadIdx.x) * 4;
  float4 v = *(const float4*)(X + i);
  u16 h0 = f2b(v.x), h1 = f2b(v.y), h2 = f2b(v.z), h3 = f2b(v.w);
  u16x4 hs = { h0, h1, h2, h3 };
  u16x4 ls = { f2b(v.x - b2f(h0)), f2b(v.y - b2f(h1)),
               f2b(v.z - b2f(h2)), f2b(v.w - b2f(h3)) };
  *(u16x4*)(Xh + i) = hs;
  *(u16x4*)(Xl + i) = ls;
}

// ---------------------------------------------------------------------------
// prep_w: W fp32 [K][N] -> WtH/WtL bf16 [N][K] (transpose + split).
// block 256 = 32x8, tile 32x32 via LDS.
// ---------------------------------------------------------------------------
__global__ __launch_bounds__(256) void prep_w_kernel(
    const float* __restrict__ W, u16* __restrict__ WtH, u16* __restrict__ WtL,
    int K, int N) {
  __shared__ float T[32][33];
  const int k0 = blockIdx.x * 32, n0 = blockIdx.y * 32;
  const int tx = threadIdx.x & 31, ty = threadIdx.x >> 5;
  #pragma unroll
  for (int i = 0; i < 4; ++i)
    T[ty + i * 8][tx] = W[(size_t)(k0 + ty + i * 8) * N + n0 + tx];
  __syncthreads();
  #pragma unroll
  for (int i = 0; i < 4; ++i) {
    const int rn = ty + i * 8, ck = tx;
    float v = T[ck][rn];
    u16 h = f2b(v);
    WtH[(size_t)(n0 + rn) * K + k0 + ck] = h;
    WtL[(size_t)(n0 + rn) * K + k0 + ck] = f2b(v - b2f(h));
  }
}

// prep_wo: Wo fp32 [K][N] -> Wot bf16 [N][K] (transpose, hi only).
__global__ __launch_bounds__(256) void prep_wo_kernel(
    const float* __restrict__ W, u16* __restrict__ Wt, int K, int N) {
  __shared__ float T[32][33];
  const int k0 = blockIdx.x * 32, n0 = blockIdx.y * 32;
  const int tx = threadIdx.x & 31, ty = threadIdx.x >> 5;
  #pragma unroll
  for (int i = 0; i < 4; ++i)
    T[ty + i * 8][tx] = W[(size_t)(k0 + ty + i * 8) * N + n0 + tx];
  __syncthreads();
  #pragma unroll
  for (int i = 0; i < 4; ++i) {
    const int rn = ty + i * 8, ck = tx;
    Wt[(size_t)(n0 + rn) * K + k0 + ck] = f2b(T[ck][rn]);
  }
}

// ---------------------------------------------------------------------------
// Kernel 1: qkv = x @ Wqkv, bf16x3 split (3 MFMAs). 128x128 tile, BK=32,
// 4 waves, global_load_lds width-16 staging of pre-split bf16 inputs.
// Q written fp32; K bf16; V bf16 transposed.
// ---------------------------------------------------------------------------
__global__ __launch_bounds__(256) void qkv_gemm_kernel(
    const u16* __restrict__ Xh, const u16* __restrict__ Xl,
    const u16* __restrict__ WtH, const u16* __restrict__ WtL,
    float* __restrict__ Qo, u16* __restrict__ Ko, u16* __restrict__ Vo) {
  __shared__ u16 Ah[4096], Al[4096], Bh[4096], Bl[4096];  // [128][32] each
  const int tid = threadIdx.x;
  const int w = tid >> 6, l = tid & 63;
  const int llo = l & 15, lhi = l >> 4;
  const int m0 = blockIdx.x * 128, n0 = blockIdx.y * 128;
  const int wr = (w >> 1) * 64, wc = (w & 1) * 64;

  f32x4 acc[4][4] = {};

  // staging: thread tid covers tile bytes [tid*16, tid*16+16) of each 64-row
  // half; row = tid>>2 (+64), u16 col = (tid&3)*8. LDS base uniform per wave.
  const int sr = tid >> 2;
  const int sc = (tid & 3) * 8;
  const unsigned lb = ((unsigned)w) * 512 + 0;  // u16 offset (w*1024 bytes)
  const u16* axh = Xh + (size_t)(m0 + sr) * 768 + sc;
  const u16* axl = Xl + (size_t)(m0 + sr) * 768 + sc;
  const u16* bwh = WtH + (size_t)(n0 + sr) * 768 + sc;
  const u16* bwl = WtL + (size_t)(n0 + sr) * 768 + sc;
  const size_t half = (size_t)64 * 768;

  for (int k0 = 0; k0 < 768; k0 += 32) {
    __syncthreads();
    gload16(axh + k0,        Ah + lb);
    gload16(axh + half + k0, Ah + 2048 + lb);
    gload16(axl + k0,        Al + lb);
    gload16(axl + half + k0, Al + 2048 + lb);
    gload16(bwh + k0,        Bh + lb);
    gload16(bwh + half + k0, Bh + 2048 + lb);
    gload16(bwl + k0,        Bl + lb);
    gload16(bwl + half + k0, Bl + 2048 + lb);
    __syncthreads();
    bf16x8 ahf[4], alf[4], bhf[4], blf[4];
    #pragma unroll
    for (int i = 0; i < 4; ++i) {
      ahf[i] = *(const bf16x8*)&Ah[(wr + i * 16 + llo) * 32 + lhi * 8];
      alf[i] = *(const bf16x8*)&Al[(wr + i * 16 + llo) * 32 + lhi * 8];
    }
    #pragma unroll
    for (int n = 0; n < 4; ++n) {
      bhf[n] = *(const bf16x8*)&Bh[(wc + n * 16 + llo) * 32 + lhi * 8];
      blf[n] = *(const bf16x8*)&Bl[(wc + n * 16 + llo) * 32 + lhi * 8];
    }
    #pragma unroll
    for (int i = 0; i < 4; ++i)
      #pragma unroll
      for (int n = 0; n < 4; ++n) {
        MFMA16(acc[i][n], ahf[i], bhf[n]);
        MFMA16(acc[i][n], alf[i], bhf[n]);
        MFMA16(acc[i][n], ahf[i], blf[n]);
      }
  }

  // Epilogue: col -> (t,h,c); t uniform per block (768 % 128 == 0).
  const int t = n0 / 768;
  #pragma unroll
  for (int i = 0; i < 4; ++i) {
    #pragma unroll
    for (int n = 0; n < 4; ++n) {
      const int gc = n0 + wc + n * 16 + llo;
      const int rem = gc - t * 768;
      const int h = rem >> 6, c = rem & 63;
      #pragma unroll
      for (int r = 0; r < 4; ++r) {
        const int row = m0 + wr + i * 16 + lhi * 4 + r;  // D: row=(l>>4)*4+reg
        const int b = row >> 11, lq = row & 2047;
        const size_t bh_ = (size_t)(b * 12 + h);
        const float fv = acc[i][n][r];
        if (t == 0)      Qo[(bh_ * 2048 + lq) * 64 + c] = fv;          // fp32
        else if (t == 1) Ko[(bh_ * 2048 + lq) * 64 + c] = f2b(fv);
        else             Vo[(bh_ * 64 + c) * 2048 + lq] = f2b(fv);     // V^T
      }
    }
  }
}

// ---------------------------------------------------------------------------
// Kernel 2: flash attention (no logit scale). Q fp32 -> hi/lo register split;
// QK^T = 2 products. 4 waves x 16 q-rows, KV tile = 64 keys in LDS.
// ---------------------------------------------------------------------------
__global__ __launch_bounds__(256) void attn_kernel(
    const float* __restrict__ Qf, const u16* __restrict__ Km,
    const u16* __restrict__ Vt, u16* __restrict__ AO) {
  __shared__ u16 Ks[64][72];
  __shared__ u16 Vs[64][72];
  __shared__ u16 Ps[4][16][72];
  const int tid = threadIdx.x;
  const int w = tid >> 6, l = tid & 63;
  const int llo = l & 15, lhi = l >> 4;
  const int bh = blockIdx.y;
  const int q0 = blockIdx.x * 64 + w * 16;

  const float* Qp = Qf + ((size_t)bh * 2048 + q0 + llo) * 64 + lhi * 8;
  bf16x8 qf0h, qf0l, qf1h, qf1l;
  #pragma unroll
  for (int j = 0; j < 8; ++j) {
    float a = Qp[j], b = Qp[32 + j];
    u16 ha = f2b(a), hb = f2b(b);
    qf0h[j] = (short)ha; qf0l[j] = (short)f2b(a - b2f(ha));
    qf1h[j] = (short)hb; qf1l[j] = (short)f2b(b - b2f(hb));
  }

  float mrow[4], lsum[4];
  f32x4 o_acc[4] = {};
  #pragma unroll
  for (int r = 0; r < 4; ++r) { mrow[r] = -1e30f; lsum[r] = 0.f; }

  for (int kt = 0; kt < 32; ++kt) {
    const int kb = kt * 64;
    __syncthreads();
    #pragma unroll
    for (int i = 0; i < 2; ++i) {
      const int idx = tid + i * 256;
      const int r = idx >> 3, ch = (idx & 7) * 8;
      *(u16x8*)&Ks[r][ch] = *(const u16x8*)(Km + ((size_t)bh * 2048 + kb + r) * 64 + ch);
      *(u16x8*)&Vs[r][ch] = *(const u16x8*)(Vt + ((size_t)bh * 64 + r) * 2048 + kb + ch);
    }
    __syncthreads();

    f32x4 s_acc[4] = {};
    #pragma unroll
    for (int kb4 = 0; kb4 < 4; ++kb4) {
      bf16x8 kf0 = *(const bf16x8*)&Ks[kb4 * 16 + llo][lhi * 8];
      bf16x8 kf1 = *(const bf16x8*)&Ks[kb4 * 16 + llo][32 + lhi * 8];
      MFMA16(s_acc[kb4], qf0h, kf0);
      MFMA16(s_acc[kb4], qf0l, kf0);
      MFMA16(s_acc[kb4], qf1h, kf1);
      MFMA16(s_acc[kb4], qf1l, kf1);
    }

    #pragma unroll
    for (int r = 0; r < 4; ++r) {
      float tm = fmaxf(fmaxf(s_acc[0][r], s_acc[1][r]),
                       fmaxf(s_acc[2][r], s_acc[3][r]));
      tm = fmaxf(tm, __shfl_xor(tm, 1));
      tm = fmaxf(tm, __shfl_xor(tm, 2));
      tm = fmaxf(tm, __shfl_xor(tm, 4));
      tm = fmaxf(tm, __shfl_xor(tm, 8));
      const float mn = fmaxf(mrow[r], tm);
      const float scale = __expf(mrow[r] - mn);
      mrow[r] = mn;
      float rs = 0.f;
      #pragma unroll
      for (int kb4 = 0; kb4 < 4; ++kb4) {
        const float p = __expf(s_acc[kb4][r] - mn);
        rs += p;
        Ps[w][lhi * 4 + r][kb4 * 16 + llo] = f2b(p);
      }
      rs += __shfl_xor(rs, 1);
      rs += __shfl_xor(rs, 2);
      rs += __shfl_xor(rs, 4);
      rs += __shfl_xor(rs, 8);
      lsum[r] = lsum[r] * scale + rs;
      #pragma unroll
      for (int cb = 0; cb < 4; ++cb) o_acc[cb][r] *= scale;
    }

    const bf16x8 pa0 = *(const bf16x8*)&Ps[w][llo][lhi * 8];
    const bf16x8 pa1 = *(const bf16x8*)&Ps[w][llo][32 + lhi * 8];
    #pragma unroll
    for (int cb = 0; cb < 4; ++cb) {
      bf16x8 vf0 = *(const bf16x8*)&Vs[cb * 16 + llo][lhi * 8];
      bf16x8 vf1 = *(const bf16x8*)&Vs[cb * 16 + llo][32 + lhi * 8];
      MFMA16(o_acc[cb], pa0, vf0);
      MFMA16(o_acc[cb], pa1, vf1);
    }
  }

  const int b = bh / 12, h = bh % 12;
  #pragma unroll
  for (int cb = 0; cb < 4; ++cb)
    #pragma unroll
    for (int r = 0; r < 4; ++r) {
      const float val = o_acc[cb][r] / lsum[r];
      AO[((size_t)(b * 2048 + q0 + lhi * 4 + r)) * 768 + h * 64 + cb * 16 + llo] = f2b(val);
    }
}

// ---------------------------------------------------------------------------
// Kernel 3: out = AO @ Wot^T + bo, m97-style staging. fp32 out.
// ---------------------------------------------------------------------------
__global__ __launch_bounds__(256) void out_gemm_kernel(
    const u16* __restrict__ A, const u16* __restrict__ Wot,
    const float* __restrict__ bias, float* __restrict__ Out) {
  __shared__ u16 As[4096], Bs[4096];
  const int tid = threadIdx.x;
  const int w = tid >> 6, l = tid & 63;
  const int llo = l & 15, lhi = l >> 4;
  const int m0 = blockIdx.x * 128, n0 = blockIdx.y * 128;
  const int wr = (w >> 1) * 64, wc = (w & 1) * 64;

  f32x4 acc[4][4] = {};

  const int sr = tid >> 2;
  const int sc = (tid & 3) * 8;
  const unsigned lb = ((unsigned)w) * 512;
  const u16* ap = A   + (size_t)(m0 + sr) * 768 + sc;
  const u16* bp = Wot + (size_t)(n0 + sr) * 768 + sc;
  const size_t half = (size_t)64 * 768;

  for (int k0 = 0; k0 < 768; k0 += 32) {
    __syncthreads();
    gload16(ap + k0,        As + lb);
    gload16(ap + half + k0, As + 2048 + lb);
    gload16(bp + k0,        Bs + lb);
    gload16(bp + half + k0, Bs + 2048 + lb);
    __syncthreads();
    bf16x8 af[4], bfr[4];
    #pragma unroll
    for (int i = 0; i < 4; ++i)
      af[i] = *(const bf16x8*)&As[(wr + i * 16 + llo) * 32 + lhi * 8];
    #pragma unroll
    for (int n = 0; n < 4; ++n)
      bfr[n] = *(const bf16x8*)&Bs[(wc + n * 16 + llo) * 32 + lhi * 8];
    #pragma unroll
    for (int i = 0; i < 4; ++i)
      #pragma unroll
      for (int n = 0; n < 4; ++n)
        MFMA16(acc[i][n], af[i], bfr[n]);
  }

  #pragma unroll
  for (int i = 0; i < 4; ++i)
    #pragma unroll
    for (int n = 0; n < 4; ++n) {
      const int gc = n0 + wc + n * 16 + llo;
      const float bb = bias[gc];
      #pragma unroll
      for (int r = 0; r < 4; ++r) {
        const int row = m0 + wr + i * 16 + lhi * 4 + r;
        Out[(size_t)row * 768 + gc] = acc[i][n][r] + bb;
      }
    }
}

// ---------------------------------------------------------------------------
extern "C" void kernel_launch(void* const* d_in, const int* in_sizes, int n_in,
                              void* d_out, int out_size, void* d_ws, size_t ws_size,
                              hipStream_t stream) {
  const float* x    = (const float*)d_in[0];
  const float* Wqkv = (const float*)d_in[1];
  const float* Wo   = (const float*)d_in[2];
  const float* bo   = (const float*)d_in[3];
  float* out = (float*)d_out;

  const size_t SEG = (size_t)48 * 2048 * 64;  // 6291456
  float* qf  = (float*)d_ws;                  // [SEG] fp32
  u16* kk    = (u16*)(qf + SEG);              // [SEG]
  u16* vt    = kk + SEG;                      // [SEG]
  u16* xh    = vt + SEG;                      // [SEG]  (becomes AO)
  u16* xl    = xh + SEG;                      // [SEG]
  u16* wth   = xl + SEG;                      // [2304*768]
  u16* wtl   = wth + (size_t)2304 * 768;
  u16* wot   = wtl + (size_t)2304 * 768;      // [768*768]
  u16* ao    = xh;                            // alias: Xh dead after qkv_gemm

  prep_x_kernel <<<dim3(6144), 256, 0, stream>>>(x, xh, xl);
  prep_w_kernel <<<dim3(24, 72), 256, 0, stream>>>(Wqkv, wth, wtl, 768, 2304);
  prep_wo_kernel<<<dim3(24, 24), 256, 0, stream>>>(Wo, wot, 768, 768);
  qkv_gemm_kernel<<<dim3(64, 18), 256, 0, stream>>>(xh, xl, wth, wtl, qf, kk, vt);
  attn_kernel   <<<dim3(32, 48), 256, 0, stream>>>(qf, kk, vt, ao);
  out_gemm_kernel<<<dim3(64, 6), 256, 0, stream>>>(ao, wot, bo, out);
}

// Round 4
// 271.511 us; speedup vs baseline: 1.4830x; 1.1567x over previous
//
#include <hip/hip_runtime.h>
#include <hip/hip_bf16.h>

// B=4, L=2048, DIM=768, H=12, C=64.  M = B*L = 8192.  BH = 48.
// ws (u16 units), SEG = 48*2048*64 = 6291456:
//   Qf32[2S] | K[S] | Vt[S] | Xh[S] (reused as AO after qkv) | Xl[S]
//   | WtH[2304*768] | WtL[2304*768] | Wot[768*768]   ~= 84 MB

typedef unsigned short u16;
typedef u16 u16x2 __attribute__((ext_vector_type(2)));
typedef u16 u16x4 __attribute__((ext_vector_type(4)));
typedef u16 u16x8 __attribute__((ext_vector_type(8)));
typedef short bf16x8 __attribute__((ext_vector_type(8)));
typedef float f32x4 __attribute__((ext_vector_type(4)));

#define MFMA16(acc, a, b) \
  asm("v_mfma_f32_16x16x32_bf16 %0, %1, %2, %0" : "+v"(acc) : "v"(a), "v"(b))

__device__ __forceinline__ u16 f2b(float f) {  // fp32 -> bf16 RNE
  unsigned u = __float_as_uint(f);
  return (u16)((u + 0x7fffu + ((u >> 16) & 1u)) >> 16);
}
__device__ __forceinline__ float b2f(u16 h) {
  return __uint_as_float(((unsigned)h) << 16);
}
__device__ __forceinline__ unsigned pk_bf16(float a, float b) {
  unsigned d;
  asm("v_cvt_pk_bf16_f32 %0, %1, %2" : "=v"(d) : "v"(a), "v"(b));
  return d;  // low16 = bf16(a), high16 = bf16(b)
}

// async global->LDS, 16B per lane. LDS dest must be wave-uniform base.
__device__ __forceinline__ void gload16(const u16* g, u16* l) {
  __builtin_amdgcn_global_load_lds(
      (const __attribute__((address_space(1))) unsigned*)g,
      (__attribute__((address_space(3))) unsigned*)l, 16, 0, 0);
}

// ---------------------------------------------------------------------------
// prep_x: x fp32 [8192][768] -> Xh, Xl bf16 (Dekker hi/lo). 4 elems/thread.
// ---------------------------------------------------------------------------
__global__ __launch_bounds__(256) void prep_x_kernel(
    const float* __restrict__ X, u16* __restrict__ Xh, u16* __restrict__ Xl) {
  const size_t i = ((size_t)blockIdx.x * 256 + threadIdx.x) * 4;
  float4 v = *(const float4*)(X + i);
  u16 h0 = f2b(v.x), h1 = f2b(v.y), h2 = f2b(v.z), h3 = f2b(v.w);
  u16x4 hs = { h0, h1, h2, h3 };
  u16x4 ls = { f2b(v.x - b2f(h0)), f2b(v.y - b2f(h1)),
               f2b(v.z - b2f(h2)), f2b(v.w - b2f(h3)) };
  *(u16x4*)(Xh + i) = hs;
  *(u16x4*)(Xl + i) = ls;
}

// ---------------------------------------------------------------------------
// prep_w: W fp32 [K][N] -> WtH/WtL bf16 [N][K] (transpose + split).
// ---------------------------------------------------------------------------
__global__ __launch_bounds__(256) void prep_w_kernel(
    const float* __restrict__ W, u16* __restrict__ WtH, u16* __restrict__ WtL,
    int K, int N) {
  __shared__ float T[32][33];
  const int k0 = blockIdx.x * 32, n0 = blockIdx.y * 32;
  const int tx = threadIdx.x & 31, ty = threadIdx.x >> 5;
  #pragma unroll
  for (int i = 0; i < 4; ++i)
    T[ty + i * 8][tx] = W[(size_t)(k0 + ty + i * 8) * N + n0 + tx];
  __syncthreads();
  #pragma unroll
  for (int i = 0; i < 4; ++i) {
    const int rn = ty + i * 8, ck = tx;
    float v = T[ck][rn];
    u16 h = f2b(v);
    WtH[(size_t)(n0 + rn) * K + k0 + ck] = h;
    WtL[(size_t)(n0 + rn) * K + k0 + ck] = f2b(v - b2f(h));
  }
}

// prep_wo: Wo fp32 [K][N] -> Wot bf16 [N][K] (transpose, hi only).
__global__ __launch_bounds__(256) void prep_wo_kernel(
    const float* __restrict__ W, u16* __restrict__ Wt, int K, int N) {
  __shared__ float T[32][33];
  const int k0 = blockIdx.x * 32, n0 = blockIdx.y * 32;
  const int tx = threadIdx.x & 31, ty = threadIdx.x >> 5;
  #pragma unroll
  for (int i = 0; i < 4; ++i)
    T[ty + i * 8][tx] = W[(size_t)(k0 + ty + i * 8) * N + n0 + tx];
  __syncthreads();
  #pragma unroll
  for (int i = 0; i < 4; ++i) {
    const int rn = ty + i * 8, ck = tx;
    Wt[(size_t)(n0 + rn) * K + k0 + ck] = f2b(T[ck][rn]);
  }
}

// ---------------------------------------------------------------------------
// Kernel 1: qkv = x @ Wqkv, bf16x3 split (3 MFMAs). 128x128 tile, BK=32,
// 4 waves, global_load_lds width-16 staging of pre-split bf16 inputs.
// ---------------------------------------------------------------------------
__global__ __launch_bounds__(256) void qkv_gemm_kernel(
    const u16* __restrict__ Xh, const u16* __restrict__ Xl,
    const u16* __restrict__ WtH, const u16* __restrict__ WtL,
    float* __restrict__ Qo, u16* __restrict__ Ko, u16* __restrict__ Vo) {
  __shared__ u16 Ah[4096], Al[4096], Bh[4096], Bl[4096];  // [128][32] each
  const int tid = threadIdx.x;
  const int w = tid >> 6, l = tid & 63;
  const int llo = l & 15, lhi = l >> 4;
  const int m0 = blockIdx.x * 128, n0 = blockIdx.y * 128;
  const int wr = (w >> 1) * 64, wc = (w & 1) * 64;

  f32x4 acc[4][4] = {};

  const int sr = tid >> 2;
  const int sc = (tid & 3) * 8;
  const unsigned lb = ((unsigned)w) * 512;
  const u16* axh = Xh + (size_t)(m0 + sr) * 768 + sc;
  const u16* axl = Xl + (size_t)(m0 + sr) * 768 + sc;
  const u16* bwh = WtH + (size_t)(n0 + sr) * 768 + sc;
  const u16* bwl = WtL + (size_t)(n0 + sr) * 768 + sc;
  const size_t half = (size_t)64 * 768;

  for (int k0 = 0; k0 < 768; k0 += 32) {
    __syncthreads();
    gload16(axh + k0,        Ah + lb);
    gload16(axh + half + k0, Ah + 2048 + lb);
    gload16(axl + k0,        Al + lb);
    gload16(axl + half + k0, Al + 2048 + lb);
    gload16(bwh + k0,        Bh + lb);
    gload16(bwh + half + k0, Bh + 2048 + lb);
    gload16(bwl + k0,        Bl + lb);
    gload16(bwl + half + k0, Bl + 2048 + lb);
    __syncthreads();
    bf16x8 ahf[4], alf[4], bhf[4], blf[4];
    #pragma unroll
    for (int i = 0; i < 4; ++i) {
      ahf[i] = *(const bf16x8*)&Ah[(wr + i * 16 + llo) * 32 + lhi * 8];
      alf[i] = *(const bf16x8*)&Al[(wr + i * 16 + llo) * 32 + lhi * 8];
    }
    #pragma unroll
    for (int n = 0; n < 4; ++n) {
      bhf[n] = *(const bf16x8*)&Bh[(wc + n * 16 + llo) * 32 + lhi * 8];
      blf[n] = *(const bf16x8*)&Bl[(wc + n * 16 + llo) * 32 + lhi * 8];
    }
    #pragma unroll
    for (int i = 0; i < 4; ++i)
      #pragma unroll
      for (int n = 0; n < 4; ++n) {
        MFMA16(acc[i][n], ahf[i], bhf[n]);
        MFMA16(acc[i][n], alf[i], bhf[n]);
        MFMA16(acc[i][n], ahf[i], blf[n]);
      }
  }

  const int t = n0 / 768;
  #pragma unroll
  for (int i = 0; i < 4; ++i) {
    #pragma unroll
    for (int n = 0; n < 4; ++n) {
      const int gc = n0 + wc + n * 16 + llo;
      const int rem = gc - t * 768;
      const int h = rem >> 6, c = rem & 63;
      #pragma unroll
      for (int r = 0; r < 4; ++r) {
        const int row = m0 + wr + i * 16 + lhi * 4 + r;
        const int b = row >> 11, lq = row & 2047;
        const size_t bh_ = (size_t)(b * 12 + h);
        const float fv = acc[i][n][r];
        if (t == 0)      Qo[(bh_ * 2048 + lq) * 64 + c] = fv;
        else if (t == 1) Ko[(bh_ * 2048 + lq) * 64 + c] = f2b(fv);
        else             Vo[(bh_ * 64 + c) * 2048 + lq] = f2b(fv);
      }
    }
  }
}

// ---------------------------------------------------------------------------
// Kernel 2: flash attention, swapped-QK in-lane softmax + defer-max.
// S^T = mfma(A=K, B=Q): lane holds S[16 keys][q=llo]; row reduce = in-lane
// + 2 shfl across the 4-lane q-group (lanes llo, llo+16, llo+32, llo+48).
// ---------------------------------------------------------------------------
__global__ __launch_bounds__(256) void attn_kernel(
    const float* __restrict__ Qf, const u16* __restrict__ Km,
    const u16* __restrict__ Vt, u16* __restrict__ AO) {
  __shared__ u16 Ks[64][72];
  __shared__ u16 Vs[64][72];
  __shared__ u16 Ps[4][16][72];   // [wave][q][key]
  const int tid = threadIdx.x;
  const int w = tid >> 6, l = tid & 63;
  const int llo = l & 15, lhi = l >> 4;
  const int bh = blockIdx.y;
  const int q0 = blockIdx.x * 64 + w * 16;

  // Q fragments: lane holds Q[q=llo][c=lhi*8+j] -> valid as MFMA B-operand
  const float* Qp = Qf + ((size_t)bh * 2048 + q0 + llo) * 64 + lhi * 8;
  bf16x8 qf0h, qf0l, qf1h, qf1l;
  #pragma unroll
  for (int j = 0; j < 8; ++j) {
    float a = Qp[j], b = Qp[32 + j];
    u16 ha = f2b(a), hb = f2b(b);
    qf0h[j] = (short)ha; qf0l[j] = (short)f2b(a - b2f(ha));
    qf1h[j] = (short)hb; qf1l[j] = (short)f2b(b - b2f(hb));
  }

  const float L2E = 1.4426950408889634f;
  float mrow = -1e30f, lsum = 0.f;   // per-lane, for q = llo
  f32x4 o_acc[4] = {};               // O[q=lhi*4+r][c=cb*16+llo]

  for (int kt = 0; kt < 32; ++kt) {
    const int kb = kt * 64;
    __syncthreads();
    #pragma unroll
    for (int i = 0; i < 2; ++i) {
      const int idx = tid + i * 256;
      const int r = idx >> 3, ch = (idx & 7) * 8;
      *(u16x8*)&Ks[r][ch] = *(const u16x8*)(Km + ((size_t)bh * 2048 + kb + r) * 64 + ch);
      *(u16x8*)&Vs[r][ch] = *(const u16x8*)(Vt + ((size_t)bh * 64 + r) * 2048 + kb + ch);
    }
    __syncthreads();

    // S^T: s_acc[kb4] reg r = S[key = kb4*16 + lhi*4 + r][q = llo]
    f32x4 s_acc[4] = {};
    #pragma unroll
    for (int kb4 = 0; kb4 < 4; ++kb4) {
      bf16x8 kf0 = *(const bf16x8*)&Ks[kb4 * 16 + llo][lhi * 8];
      bf16x8 kf1 = *(const bf16x8*)&Ks[kb4 * 16 + llo][32 + lhi * 8];
      MFMA16(s_acc[kb4], kf0, qf0h);
      MFMA16(s_acc[kb4], kf0, qf0l);
      MFMA16(s_acc[kb4], kf1, qf1h);
      MFMA16(s_acc[kb4], kf1, qf1l);
    }

    // in-lane tile max (16 values) + 2-shfl group reduce
    float tm01 = fmaxf(fmaxf(s_acc[0][0], s_acc[0][1]), fmaxf(s_acc[0][2], s_acc[0][3]));
    float tm23 = fmaxf(fmaxf(s_acc[1][0], s_acc[1][1]), fmaxf(s_acc[1][2], s_acc[1][3]));
    float tm45 = fmaxf(fmaxf(s_acc[2][0], s_acc[2][1]), fmaxf(s_acc[2][2], s_acc[2][3]));
    float tm67 = fmaxf(fmaxf(s_acc[3][0], s_acc[3][1]), fmaxf(s_acc[3][2], s_acc[3][3]));
    float tm = fmaxf(fmaxf(tm01, tm23), fmaxf(tm45, tm67));
    tm = fmaxf(tm, __shfl_xor(tm, 16));
    tm = fmaxf(tm, __shfl_xor(tm, 32));

    // defer-max: rescale only when the running max grew by > 8
    if (!__all(tm <= mrow + 8.f)) {
      const float mn = fmaxf(mrow, tm);
      const float scale = __expf(mrow - mn);
      mrow = mn;
      lsum *= scale;
      float scr[4];
      #pragma unroll
      for (int r = 0; r < 4; ++r) scr[r] = __shfl(scale, lhi * 20 + r);
      #pragma unroll
      for (int cb = 0; cb < 4; ++cb)
        #pragma unroll
        for (int r = 0; r < 4; ++r) o_acc[cb][r] *= scr[r];
    }

    // P = exp(S - mrow), packed bf16 stores (4x 8B per lane)
    const float mb = mrow * L2E;
    float rs = 0.f;
    #pragma unroll
    for (int kb4 = 0; kb4 < 4; ++kb4) {
      float p0 = exp2f(fmaf(s_acc[kb4][0], L2E, -mb));
      float p1 = exp2f(fmaf(s_acc[kb4][1], L2E, -mb));
      float p2 = exp2f(fmaf(s_acc[kb4][2], L2E, -mb));
      float p3 = exp2f(fmaf(s_acc[kb4][3], L2E, -mb));
      rs += (p0 + p1) + (p2 + p3);
      uint2 pk = { pk_bf16(p0, p1), pk_bf16(p2, p3) };
      *(uint2*)&Ps[w][llo][kb4 * 16 + lhi * 4] = pk;
    }
    rs += __shfl_xor(rs, 16);
    rs += __shfl_xor(rs, 32);
    lsum += rs;

    // O += P V : pa = A[q=llo][key=lhi*8+j] (same-wave LDS round-trip)
    const bf16x8 pa0 = *(const bf16x8*)&Ps[w][llo][lhi * 8];
    const bf16x8 pa1 = *(const bf16x8*)&Ps[w][llo][32 + lhi * 8];
    #pragma unroll
    for (int cb = 0; cb < 4; ++cb) {
      bf16x8 vf0 = *(const bf16x8*)&Vs[cb * 16 + llo][lhi * 8];
      bf16x8 vf1 = *(const bf16x8*)&Vs[cb * 16 + llo][32 + lhi * 8];
      MFMA16(o_acc[cb], pa0, vf0);
      MFMA16(o_acc[cb], pa1, vf1);
    }
  }

  // normalize (lsum redistributed to D rows) + write AO bf16
  float ls[4];
  #pragma unroll
  for (int r = 0; r < 4; ++r) ls[r] = __shfl(lsum, lhi * 20 + r);
  const int b = bh / 12, h = bh % 12;
  #pragma unroll
  for (int cb = 0; cb < 4; ++cb)
    #pragma unroll
    for (int r = 0; r < 4; ++r) {
      const float val = o_acc[cb][r] / ls[r];
      AO[((size_t)(b * 2048 + q0 + lhi * 4 + r)) * 768 + h * 64 + cb * 16 + llo] = f2b(val);
    }
}

// ---------------------------------------------------------------------------
// Kernel 3: out = AO @ Wot^T + bo, m97-style staging. fp32 out.
// ---------------------------------------------------------------------------
__global__ __launch_bounds__(256) void out_gemm_kernel(
    const u16* __restrict__ A, const u16* __restrict__ Wot,
    const float* __restrict__ bias, float* __restrict__ Out) {
  __shared__ u16 As[4096], Bs[4096];
  const int tid = threadIdx.x;
  const int w = tid >> 6, l = tid & 63;
  const int llo = l & 15, lhi = l >> 4;
  const int m0 = blockIdx.x * 128, n0 = blockIdx.y * 128;
  const int wr = (w >> 1) * 64, wc = (w & 1) * 64;

  f32x4 acc[4][4] = {};

  const int sr = tid >> 2;
  const int sc = (tid & 3) * 8;
  const unsigned lb = ((unsigned)w) * 512;
  const u16* ap = A   + (size_t)(m0 + sr) * 768 + sc;
  const u16* bp = Wot + (size_t)(n0 + sr) * 768 + sc;
  const size_t half = (size_t)64 * 768;

  for (int k0 = 0; k0 < 768; k0 += 32) {
    __syncthreads();
    gload16(ap + k0,        As + lb);
    gload16(ap + half + k0, As + 2048 + lb);
    gload16(bp + k0,        Bs + lb);
    gload16(bp + half + k0, Bs + 2048 + lb);
    __syncthreads();
    bf16x8 af[4], bfr[4];
    #pragma unroll
    for (int i = 0; i < 4; ++i)
      af[i] = *(const bf16x8*)&As[(wr + i * 16 + llo) * 32 + lhi * 8];
    #pragma unroll
    for (int n = 0; n < 4; ++n)
      bfr[n] = *(const bf16x8*)&Bs[(wc + n * 16 + llo) * 32 + lhi * 8];
    #pragma unroll
    for (int i = 0; i < 4; ++i)
      #pragma unroll
      for (int n = 0; n < 4; ++n)
        MFMA16(acc[i][n], af[i], bfr[n]);
  }

  #pragma unroll
  for (int i = 0; i < 4; ++i)
    #pragma unroll
    for (int n = 0; n < 4; ++n) {
      const int gc = n0 + wc + n * 16 + llo;
      const float bb = bias[gc];
      #pragma unroll
      for (int r = 0; r < 4; ++r) {
        const int row = m0 + wr + i * 16 + lhi * 4 + r;
        Out[(size_t)row * 768 + gc] = acc[i][n][r] + bb;
      }
    }
}

// ---------------------------------------------------------------------------
extern "C" void kernel_launch(void* const* d_in, const int* in_sizes, int n_in,
                              void* d_out, int out_size, void* d_ws, size_t ws_size,
                              hipStream_t stream) {
  const float* x    = (const float*)d_in[0];
  const float* Wqkv = (const float*)d_in[1];
  const float* Wo   = (const float*)d_in[2];
  const float* bo   = (const float*)d_in[3];
  float* out = (float*)d_out;

  const size_t SEG = (size_t)48 * 2048 * 64;  // 6291456
  float* qf  = (float*)d_ws;                  // [SEG] fp32
  u16* kk    = (u16*)(qf + SEG);              // [SEG]
  u16* vt    = kk + SEG;                      // [SEG]
  u16* xh    = vt + SEG;                      // [SEG]  (becomes AO)
  u16* xl    = xh + SEG;                      // [SEG]
  u16* wth   = xl + SEG;                      // [2304*768]
  u16* wtl   = wth + (size_t)2304 * 768;
  u16* wot   = wtl + (size_t)2304 * 768;      // [768*768]
  u16* ao    = xh;                            // alias: Xh dead after qkv_gemm

  prep_x_kernel <<<dim3(6144), 256, 0, stream>>>(x, xh, xl);
  prep_w_kernel <<<dim3(24, 72), 256, 0, stream>>>(Wqkv, wth, wtl, 768, 2304);
  prep_wo_kernel<<<dim3(24, 24), 256, 0, stream>>>(Wo, wot, 768, 768);
  qkv_gemm_kernel<<<dim3(64, 18), 256, 0, stream>>>(xh, xl, wth, wtl, qf, kk, vt);
  attn_kernel   <<<dim3(32, 48), 256, 0, stream>>>(qf, kk, vt, ao);
  out_gemm_kernel<<<dim3(64, 6), 256, 0, stream>>>(ao, wot, bo, out);
}

// Round 5
// 258.286 us; speedup vs baseline: 1.5589x; 1.0512x over previous
//
#include <hip/hip_runtime.h>
#include <hip/hip_bf16.h>

// B=4, L=2048, DIM=768, H=12, C=64.  M = B*L = 8192.  BH = 48.
// ws (u16 units), SEG = 48*2048*64 = 6291456:
//   Qf32[2S] | K[S] | Vt[S] | Xh[S] (reused as AO after qkv) | Xl[S]
//   | WtH[2304*768] | WtL[2304*768] | Wot[768*768]   ~= 84 MB

typedef unsigned short u16;
typedef u16 u16x2 __attribute__((ext_vector_type(2)));
typedef u16 u16x4 __attribute__((ext_vector_type(4)));
typedef u16 u16x8 __attribute__((ext_vector_type(8)));
typedef short bf16x8 __attribute__((ext_vector_type(8)));
typedef float f32x4 __attribute__((ext_vector_type(4)));

#define MFMA16(acc, a, b) \
  asm("v_mfma_f32_16x16x32_bf16 %0, %1, %2, %0" : "+v"(acc) : "v"(a), "v"(b))

__device__ __forceinline__ u16 f2b(float f) {  // fp32 -> bf16 RNE
  unsigned u = __float_as_uint(f);
  return (u16)((u + 0x7fffu + ((u >> 16) & 1u)) >> 16);
}
__device__ __forceinline__ float b2f(u16 h) {
  return __uint_as_float(((unsigned)h) << 16);
}
__device__ __forceinline__ unsigned pk_bf16(float a, float b) {
  unsigned d;
  asm("v_cvt_pk_bf16_f32 %0, %1, %2" : "=v"(d) : "v"(a), "v"(b));
  return d;  // low16 = bf16(a), high16 = bf16(b)
}

// async global->LDS, 16B per lane. LDS dest must be wave-uniform base.
__device__ __forceinline__ void gload16(const u16* g, u16* l) {
  __builtin_amdgcn_global_load_lds(
      (const __attribute__((address_space(1))) unsigned*)g,
      (__attribute__((address_space(3))) unsigned*)l, 16, 0, 0);
}

// ---------------------------------------------------------------------------
// prep_x: x fp32 [8192][768] -> Xh, Xl bf16 (Dekker hi/lo). 4 elems/thread.
// ---------------------------------------------------------------------------
__global__ __launch_bounds__(256) void prep_x_kernel(
    const float* __restrict__ X, u16* __restrict__ Xh, u16* __restrict__ Xl) {
  const size_t i = ((size_t)blockIdx.x * 256 + threadIdx.x) * 4;
  float4 v = *(const float4*)(X + i);
  u16 h0 = f2b(v.x), h1 = f2b(v.y), h2 = f2b(v.z), h3 = f2b(v.w);
  u16x4 hs = { h0, h1, h2, h3 };
  u16x4 ls = { f2b(v.x - b2f(h0)), f2b(v.y - b2f(h1)),
               f2b(v.z - b2f(h2)), f2b(v.w - b2f(h3)) };
  *(u16x4*)(Xh + i) = hs;
  *(u16x4*)(Xl + i) = ls;
}

// ---------------------------------------------------------------------------
// prep_w: W fp32 [K][N] -> WtH/WtL bf16 [N][K] (transpose + split).
// ---------------------------------------------------------------------------
__global__ __launch_bounds__(256) void prep_w_kernel(
    const float* __restrict__ W, u16* __restrict__ WtH, u16* __restrict__ WtL,
    int K, int N) {
  __shared__ float T[32][33];
  const int k0 = blockIdx.x * 32, n0 = blockIdx.y * 32;
  const int tx = threadIdx.x & 31, ty = threadIdx.x >> 5;
  #pragma unroll
  for (int i = 0; i < 4; ++i)
    T[ty + i * 8][tx] = W[(size_t)(k0 + ty + i * 8) * N + n0 + tx];
  __syncthreads();
  #pragma unroll
  for (int i = 0; i < 4; ++i) {
    const int rn = ty + i * 8, ck = tx;
    float v = T[ck][rn];
    u16 h = f2b(v);
    WtH[(size_t)(n0 + rn) * K + k0 + ck] = h;
    WtL[(size_t)(n0 + rn) * K + k0 + ck] = f2b(v - b2f(h));
  }
}

// prep_wo: Wo fp32 [K][N] -> Wot bf16 [N][K] (transpose, hi only).
__global__ __launch_bounds__(256) void prep_wo_kernel(
    const float* __restrict__ W, u16* __restrict__ Wt, int K, int N) {
  __shared__ float T[32][33];
  const int k0 = blockIdx.x * 32, n0 = blockIdx.y * 32;
  const int tx = threadIdx.x & 31, ty = threadIdx.x >> 5;
  #pragma unroll
  for (int i = 0; i < 4; ++i)
    T[ty + i * 8][tx] = W[(size_t)(k0 + ty + i * 8) * N + n0 + tx];
  __syncthreads();
  #pragma unroll
  for (int i = 0; i < 4; ++i) {
    const int rn = ty + i * 8, ck = tx;
    Wt[(size_t)(n0 + rn) * K + k0 + ck] = f2b(T[ck][rn]);
  }
}

// ---------------------------------------------------------------------------
// Kernel 1: qkv = x @ Wqkv, bf16x3 split (3 MFMAs). 128x128 tile, BK=32,
// 4 waves, global_load_lds width-16 staging of pre-split bf16 inputs.
// ---------------------------------------------------------------------------
__global__ __launch_bounds__(256) void qkv_gemm_kernel(
    const u16* __restrict__ Xh, const u16* __restrict__ Xl,
    const u16* __restrict__ WtH, const u16* __restrict__ WtL,
    float* __restrict__ Qo, u16* __restrict__ Ko, u16* __restrict__ Vo) {
  __shared__ u16 Ah[4096], Al[4096], Bh[4096], Bl[4096];  // [128][32] each
  const int tid = threadIdx.x;
  const int w = tid >> 6, l = tid & 63;
  const int llo = l & 15, lhi = l >> 4;
  const int m0 = blockIdx.x * 128, n0 = blockIdx.y * 128;
  const int wr = (w >> 1) * 64, wc = (w & 1) * 64;

  f32x4 acc[4][4] = {};

  const int sr = tid >> 2;
  const int sc = (tid & 3) * 8;
  const unsigned lb = ((unsigned)w) * 512;
  const u16* axh = Xh + (size_t)(m0 + sr) * 768 + sc;
  const u16* axl = Xl + (size_t)(m0 + sr) * 768 + sc;
  const u16* bwh = WtH + (size_t)(n0 + sr) * 768 + sc;
  const u16* bwl = WtL + (size_t)(n0 + sr) * 768 + sc;
  const size_t half = (size_t)64 * 768;

  for (int k0 = 0; k0 < 768; k0 += 32) {
    __syncthreads();
    gload16(axh + k0,        Ah + lb);
    gload16(axh + half + k0, Ah + 2048 + lb);
    gload16(axl + k0,        Al + lb);
    gload16(axl + half + k0, Al + 2048 + lb);
    gload16(bwh + k0,        Bh + lb);
    gload16(bwh + half + k0, Bh + 2048 + lb);
    gload16(bwl + k0,        Bl + lb);
    gload16(bwl + half + k0, Bl + 2048 + lb);
    __syncthreads();
    bf16x8 ahf[4], alf[4], bhf[4], blf[4];
    #pragma unroll
    for (int i = 0; i < 4; ++i) {
      ahf[i] = *(const bf16x8*)&Ah[(wr + i * 16 + llo) * 32 + lhi * 8];
      alf[i] = *(const bf16x8*)&Al[(wr + i * 16 + llo) * 32 + lhi * 8];
    }
    #pragma unroll
    for (int n = 0; n < 4; ++n) {
      bhf[n] = *(const bf16x8*)&Bh[(wc + n * 16 + llo) * 32 + lhi * 8];
      blf[n] = *(const bf16x8*)&Bl[(wc + n * 16 + llo) * 32 + lhi * 8];
    }
    #pragma unroll
    for (int i = 0; i < 4; ++i)
      #pragma unroll
      for (int n = 0; n < 4; ++n) {
        MFMA16(acc[i][n], ahf[i], bhf[n]);
        MFMA16(acc[i][n], alf[i], bhf[n]);
        MFMA16(acc[i][n], ahf[i], blf[n]);
      }
  }

  const int t = n0 / 768;
  #pragma unroll
  for (int i = 0; i < 4; ++i) {
    #pragma unroll
    for (int n = 0; n < 4; ++n) {
      const int gc = n0 + wc + n * 16 + llo;
      const int rem = gc - t * 768;
      const int h = rem >> 6, c = rem & 63;
      #pragma unroll
      for (int r = 0; r < 4; ++r) {
        const int row = m0 + wr + i * 16 + lhi * 4 + r;
        const int b = row >> 11, lq = row & 2047;
        const size_t bh_ = (size_t)(b * 12 + h);
        const float fv = acc[i][n][r];
        if (t == 0)      Qo[(bh_ * 2048 + lq) * 64 + c] = fv;
        else if (t == 1) Ko[(bh_ * 2048 + lq) * 64 + c] = f2b(fv);
        else             Vo[(bh_ * 64 + c) * 2048 + lq] = f2b(fv);
      }
    }
  }
}

// ---------------------------------------------------------------------------
// Kernel 2: flash attention. 8 waves x 16 q-rows = 128 q/block. Swapped-QK
// in-lane softmax + defer-max. Double-buffered K/V LDS, ONE barrier per
// tile, next-tile global loads issued BEFORE compute (latency hides under
// QK+softmax+PV; compiler places the vmcnt wait at the dependent ds_write).
// ---------------------------------------------------------------------------
__global__ __launch_bounds__(512, 4) void attn_kernel(
    const float* __restrict__ Qf, const u16* __restrict__ Km,
    const u16* __restrict__ Vt, u16* __restrict__ AO) {
  __shared__ u16 Ks[2][64][72];
  __shared__ u16 Vs[2][64][72];
  __shared__ u16 Ps[8][16][72];   // [wave][q][key]
  const int tid = threadIdx.x;
  const int w = tid >> 6, l = tid & 63;
  const int llo = l & 15, lhi = l >> 4;
  const int bh = blockIdx.y;
  const int q0 = blockIdx.x * 128 + w * 16;

  // staging coords: 512 threads cover one 64x64 bf16 tile with 16B each
  const int kr = tid >> 3, ch = (tid & 7) * 8;
  const u16* Kp = Km + ((size_t)bh * 2048 + kr) * 64 + ch;   // +kt*64*64... row adv
  const u16* Vp = Vt + ((size_t)bh * 64 + kr) * 2048 + ch;   // +kt*64 col adv

  // Q fragments: lane holds Q[q=llo][c=lhi*8+j] -> MFMA B-operand
  const float* Qp = Qf + ((size_t)bh * 2048 + q0 + llo) * 64 + lhi * 8;
  bf16x8 qf0h, qf0l, qf1h, qf1l;
  #pragma unroll
  for (int j = 0; j < 8; ++j) {
    float a = Qp[j], b = Qp[32 + j];
    u16 ha = f2b(a), hb = f2b(b);
    qf0h[j] = (short)ha; qf0l[j] = (short)f2b(a - b2f(ha));
    qf1h[j] = (short)hb; qf1l[j] = (short)f2b(b - b2f(hb));
  }

  const float L2E = 1.4426950408889634f;
  float mrow = -1e30f, lsum = 0.f;   // per-lane, for q = llo
  f32x4 o_acc[4] = {};               // O[q=lhi*4+r][c=cb*16+llo]

  // prologue: stage tile 0 into buffer 0
  {
    u16x8 nk = *(const u16x8*)(Kp);
    u16x8 nv = *(const u16x8*)(Vp);
    *(u16x8*)&Ks[0][kr][ch] = nk;
    *(u16x8*)&Vs[0][kr][ch] = nv;
  }
  __syncthreads();

  for (int kt = 0; kt < 32; ++kt) {
    const int cur = kt & 1;
    // issue next-tile loads FIRST (consumed only by the ds_write below)
    u16x8 nk, nv;
    if (kt < 31) {
      nk = *(const u16x8*)(Kp + (size_t)(kt + 1) * 64 * 64);
      nv = *(const u16x8*)(Vp + (size_t)(kt + 1) * 64);
    }

    // S^T: s_acc[kb4] reg r = S[key = kb4*16 + lhi*4 + r][q = llo]
    f32x4 s_acc[4] = {};
    #pragma unroll
    for (int kb4 = 0; kb4 < 4; ++kb4) {
      bf16x8 kf0 = *(const bf16x8*)&Ks[cur][kb4 * 16 + llo][lhi * 8];
      bf16x8 kf1 = *(const bf16x8*)&Ks[cur][kb4 * 16 + llo][32 + lhi * 8];
      MFMA16(s_acc[kb4], kf0, qf0h);
      MFMA16(s_acc[kb4], kf0, qf0l);
      MFMA16(s_acc[kb4], kf1, qf1h);
      MFMA16(s_acc[kb4], kf1, qf1l);
    }

    // in-lane tile max (16 values) + 2-shfl group reduce
    float tm01 = fmaxf(fmaxf(s_acc[0][0], s_acc[0][1]), fmaxf(s_acc[0][2], s_acc[0][3]));
    float tm23 = fmaxf(fmaxf(s_acc[1][0], s_acc[1][1]), fmaxf(s_acc[1][2], s_acc[1][3]));
    float tm45 = fmaxf(fmaxf(s_acc[2][0], s_acc[2][1]), fmaxf(s_acc[2][2], s_acc[2][3]));
    float tm67 = fmaxf(fmaxf(s_acc[3][0], s_acc[3][1]), fmaxf(s_acc[3][2], s_acc[3][3]));
    float tm = fmaxf(fmaxf(tm01, tm23), fmaxf(tm45, tm67));
    tm = fmaxf(tm, __shfl_xor(tm, 16));
    tm = fmaxf(tm, __shfl_xor(tm, 32));

    // defer-max: rescale only when the running max grew by > 8
    if (!__all(tm <= mrow + 8.f)) {
      const float mn = fmaxf(mrow, tm);
      const float scale = __expf(mrow - mn);
      mrow = mn;
      lsum *= scale;
      float scr[4];
      #pragma unroll
      for (int r = 0; r < 4; ++r) scr[r] = __shfl(scale, lhi * 20 + r);
      #pragma unroll
      for (int cb = 0; cb < 4; ++cb)
        #pragma unroll
        for (int r = 0; r < 4; ++r) o_acc[cb][r] *= scr[r];
    }

    // P = exp(S - mrow), packed bf16 stores (4x 8B per lane)
    const float mb = mrow * L2E;
    float rs = 0.f;
    #pragma unroll
    for (int kb4 = 0; kb4 < 4; ++kb4) {
      float p0 = exp2f(fmaf(s_acc[kb4][0], L2E, -mb));
      float p1 = exp2f(fmaf(s_acc[kb4][1], L2E, -mb));
      float p2 = exp2f(fmaf(s_acc[kb4][2], L2E, -mb));
      float p3 = exp2f(fmaf(s_acc[kb4][3], L2E, -mb));
      rs += (p0 + p1) + (p2 + p3);
      uint2 pk = { pk_bf16(p0, p1), pk_bf16(p2, p3) };
      *(uint2*)&Ps[w][llo][kb4 * 16 + lhi * 4] = pk;
    }
    rs += __shfl_xor(rs, 16);
    rs += __shfl_xor(rs, 32);
    lsum += rs;

    // O += P V : pa = A[q=llo][key=lhi*8+j] (same-wave LDS round-trip)
    const bf16x8 pa0 = *(const bf16x8*)&Ps[w][llo][lhi * 8];
    const bf16x8 pa1 = *(const bf16x8*)&Ps[w][llo][32 + lhi * 8];
    #pragma unroll
    for (int cb = 0; cb < 4; ++cb) {
      bf16x8 vf0 = *(const bf16x8*)&Vs[cur][cb * 16 + llo][lhi * 8];
      bf16x8 vf1 = *(const bf16x8*)&Vs[cur][cb * 16 + llo][32 + lhi * 8];
      MFMA16(o_acc[cb], pa0, vf0);
      MFMA16(o_acc[cb], pa1, vf1);
    }

    // write next tile into the other buffer (safe: barrier at end of kt-1
    // guaranteed everyone finished reading buf[cur^1])
    if (kt < 31) {
      *(u16x8*)&Ks[cur ^ 1][kr][ch] = nk;
      *(u16x8*)&Vs[cur ^ 1][kr][ch] = nv;
    }
    __syncthreads();
  }

  // normalize (lsum redistributed to D rows) + write AO bf16
  float ls[4];
  #pragma unroll
  for (int r = 0; r < 4; ++r) ls[r] = __shfl(lsum, lhi * 20 + r);
  const int b = bh / 12, h = bh % 12;
  #pragma unroll
  for (int cb = 0; cb < 4; ++cb)
    #pragma unroll
    for (int r = 0; r < 4; ++r) {
      const float val = o_acc[cb][r] / ls[r];
      AO[((size_t)(b * 2048 + q0 + lhi * 4 + r)) * 768 + h * 64 + cb * 16 + llo] = f2b(val);
    }
}

// ---------------------------------------------------------------------------
// Kernel 3: out = AO @ Wot^T + bo, m97-style staging. fp32 out.
// ---------------------------------------------------------------------------
__global__ __launch_bounds__(256) void out_gemm_kernel(
    const u16* __restrict__ A, const u16* __restrict__ Wot,
    const float* __restrict__ bias, float* __restrict__ Out) {
  __shared__ u16 As[4096], Bs[4096];
  const int tid = threadIdx.x;
  const int w = tid >> 6, l = tid & 63;
  const int llo = l & 15, lhi = l >> 4;
  const int m0 = blockIdx.x * 128, n0 = blockIdx.y * 128;
  const int wr = (w >> 1) * 64, wc = (w & 1) * 64;

  f32x4 acc[4][4] = {};

  const int sr = tid >> 2;
  const int sc = (tid & 3) * 8;
  const unsigned lb = ((unsigned)w) * 512;
  const u16* ap = A   + (size_t)(m0 + sr) * 768 + sc;
  const u16* bp = Wot + (size_t)(n0 + sr) * 768 + sc;
  const size_t half = (size_t)64 * 768;

  for (int k0 = 0; k0 < 768; k0 += 32) {
    __syncthreads();
    gload16(ap + k0,        As + lb);
    gload16(ap + half + k0, As + 2048 + lb);
    gload16(bp + k0,        Bs + lb);
    gload16(bp + half + k0, Bs + 2048 + lb);
    __syncthreads();
    bf16x8 af[4], bfr[4];
    #pragma unroll
    for (int i = 0; i < 4; ++i)
      af[i] = *(const bf16x8*)&As[(wr + i * 16 + llo) * 32 + lhi * 8];
    #pragma unroll
    for (int n = 0; n < 4; ++n)
      bfr[n] = *(const bf16x8*)&Bs[(wc + n * 16 + llo) * 32 + lhi * 8];
    #pragma unroll
    for (int i = 0; i < 4; ++i)
      #pragma unroll
      for (int n = 0; n < 4; ++n)
        MFMA16(acc[i][n], af[i], bfr[n]);
  }

  #pragma unroll
  for (int i = 0; i < 4; ++i)
    #pragma unroll
    for (int n = 0; n < 4; ++n) {
      const int gc = n0 + wc + n * 16 + llo;
      const float bb = bias[gc];
      #pragma unroll
      for (int r = 0; r < 4; ++r) {
        const int row = m0 + wr + i * 16 + lhi * 4 + r;
        Out[(size_t)row * 768 + gc] = acc[i][n][r] + bb;
      }
    }
}

// ---------------------------------------------------------------------------
extern "C" void kernel_launch(void* const* d_in, const int* in_sizes, int n_in,
                              void* d_out, int out_size, void* d_ws, size_t ws_size,
                              hipStream_t stream) {
  const float* x    = (const float*)d_in[0];
  const float* Wqkv = (const float*)d_in[1];
  const float* Wo   = (const float*)d_in[2];
  const float* bo   = (const float*)d_in[3];
  float* out = (float*)d_out;

  const size_t SEG = (size_t)48 * 2048 * 64;  // 6291456
  float* qf  = (float*)d_ws;                  // [SEG] fp32
  u16* kk    = (u16*)(qf + SEG);              // [SEG]
  u16* vt    = kk + SEG;                      // [SEG]
  u16* xh    = vt + SEG;                      // [SEG]  (becomes AO)
  u16* xl    = xh + SEG;                      // [SEG]
  u16* wth   = xl + SEG;                      // [2304*768]
  u16* wtl   = wth + (size_t)2304 * 768;
  u16* wot   = wtl + (size_t)2304 * 768;      // [768*768]
  u16* ao    = xh;                            // alias: Xh dead after qkv_gemm

  prep_x_kernel <<<dim3(6144), 256, 0, stream>>>(x, xh, xl);
  prep_w_kernel <<<dim3(24, 72), 256, 0, stream>>>(Wqkv, wth, wtl, 768, 2304);
  prep_wo_kernel<<<dim3(24, 24), 256, 0, stream>>>(Wo, wot, 768, 768);
  qkv_gemm_kernel<<<dim3(64, 18), 256, 0, stream>>>(xh, xl, wth, wtl, qf, kk, vt);
  attn_kernel   <<<dim3(16, 48), 512, 0, stream>>>(qf, kk, vt, ao);
  out_gemm_kernel<<<dim3(64, 6), 256, 0, stream>>>(ao, wot, bo, out);
}